// Round 1
// baseline (236.604 us; speedup 1.0000x reference)
//
#include <hip/hip_runtime.h>

// CapsNet dynamic routing, MI355X. Strategy: never materialize u_hat.
//  s-pass:    s[b][jd]  = sum_ki x_bf[b][ki] * (c[i][j] * W2[jd][ki])   (MFMA GEMM, split-K over 256 chunks)
//  agree:     Z_T[jd][ki] = sum_b v_bfT[jd][b] * x_bf[b][ki]; epilogue: b_ij[j][i] += (1/B) sum_{k,d} W2*Z_T
// ws: x_bf16 32MB + W2 40MB + small stats + 20MB split-K partials (~97 MB total).

typedef __attribute__((ext_vector_type(8))) __bf16 bf16x8;
typedef __attribute__((ext_vector_type(4))) float  f32x4;
typedef __attribute__((ext_vector_type(8))) unsigned short u16x8;
typedef __attribute__((ext_vector_type(4))) unsigned short u16x4;

#define DI __device__ __forceinline__

DI float bf2f(unsigned short u){ unsigned int x = ((unsigned int)u) << 16; return __builtin_bit_cast(float, x); }
DI unsigned short f2bf(float f){
  unsigned int u = __builtin_bit_cast(unsigned int, f);
  u += 0x7fffu + ((u >> 16) & 1u);            // round-to-nearest-even
  return (unsigned short)(u >> 16);
}

constexpr int Ci = 4096, Kk = 32, Jj = 10, Dd = 16, Bb = 128;
constexpr int KI = Ci * Kk;    // 131072 flattened (k,i), ki = k*4096 + i
constexpr int JDt = Jj * Dd;   // 160, jd = j*16 + d
constexpr int NCH = 256, CK = 512;  // s-pass split-K chunks

// workspace layout (bytes)
constexpr size_t OFF_XB = 0;
constexpr size_t SZ_XB  = (size_t)Bb * KI * 2;        // 33,554,432
constexpr size_t OFF_W2 = OFF_XB + SZ_XB;
constexpr size_t SZ_W2  = (size_t)JDt * KI * 2;       // 41,943,040
constexpr size_t OFF_BT = OFF_W2 + SZ_W2;
constexpr size_t SZ_BT  = (size_t)Jj * Ci * 4;        // 163,840  (b_ij transposed [j][i])
constexpr size_t OFF_CT = OFF_BT + SZ_BT;             // c transposed [j][i]
constexpr size_t OFF_VBT = OFF_CT + SZ_BT;
constexpr size_t SZ_VBT = (size_t)JDt * Bb * 2;       // 40,960   (v bf16, [jd][b])
constexpr size_t OFF_SP = OFF_VBT + SZ_VBT;
constexpr size_t SZ_SP  = (size_t)NCH * Bb * JDt * 4; // 20,971,520
// total ~96.8 MB

// ---- pack x: f32 [B][K][C] -> bf16 [B][KI] (same flat order) ----
__global__ __launch_bounds__(256) void pack_x(const float* __restrict__ x, unsigned short* __restrict__ xbf){
  const size_t e = (size_t)blockIdx.x * 256 + threadIdx.x;   // 8 elems each
  const float4* xv = (const float4*)x;
  float4 a = xv[e*2], b = xv[e*2+1];
  u16x8 o;
  o[0]=f2bf(a.x); o[1]=f2bf(a.y); o[2]=f2bf(a.z); o[3]=f2bf(a.w);
  o[4]=f2bf(b.x); o[5]=f2bf(b.y); o[6]=f2bf(b.z); o[7]=f2bf(b.w);
  *(u16x8*)(xbf + e*8) = o;
}

// ---- pack W: f32 W[i][m] (m = jd*32+k, row len 5120) -> bf16 W2[m][i]  (pure 64x64 tiled transpose)
__global__ __launch_bounds__(256) void pack_w2(const float* __restrict__ W, unsigned short* __restrict__ w2){
  __shared__ float tile[64][65];
  const int mt = blockIdx.x % 80, it = blockIdx.x / 80;
  const int m0 = mt * 64, i0 = it * 64;
  #pragma unroll
  for(int u=0; u<4; u++){
    int e = threadIdx.x + 256*u;
    int il = e >> 4, q = e & 15;
    float4 v = *(const float4*)(W + (size_t)(i0+il)*5120 + m0 + q*4);
    tile[il][q*4+0]=v.x; tile[il][q*4+1]=v.y; tile[il][q*4+2]=v.z; tile[il][q*4+3]=v.w;
  }
  __syncthreads();
  #pragma unroll
  for(int u=0; u<4; u++){
    int e = threadIdx.x + 256*u;
    int ml = e >> 4, q = e & 15;
    u16x4 o;
    o[0]=f2bf(tile[q*4+0][ml]); o[1]=f2bf(tile[q*4+1][ml]);
    o[2]=f2bf(tile[q*4+2][ml]); o[3]=f2bf(tile[q*4+3][ml]);
    *(u16x4*)(w2 + (size_t)(m0+ml)*Ci + i0 + q*4) = o;
  }
}

// ---- softmax over i per class j: cT[j][i] = softmax_i(bT[j][i]) ----
__global__ __launch_bounds__(256) void softmax_k(const float* __restrict__ bT, float* __restrict__ cT){
  const int j = blockIdx.x, tid = threadIdx.x, lane = tid & 63, wid = tid >> 6;
  __shared__ float red[4];
  float vals[16];
  float mx = -3.4e38f;
  #pragma unroll
  for(int u=0; u<16; u++){ vals[u] = bT[j*Ci + tid + 256*u]; mx = fmaxf(mx, vals[u]); }
  #pragma unroll
  for(int o=32; o>0; o>>=1) mx = fmaxf(mx, __shfl_xor(mx, o));
  if(lane == 0) red[wid] = mx;
  __syncthreads();
  mx = fmaxf(fmaxf(red[0],red[1]), fmaxf(red[2],red[3]));
  float sm = 0.f;
  #pragma unroll
  for(int u=0; u<16; u++){ vals[u] = expf(vals[u]-mx); sm += vals[u]; }
  #pragma unroll
  for(int o=32; o>0; o>>=1) sm += __shfl_xor(sm, o);
  __syncthreads();
  if(lane == 0) red[wid] = sm;
  __syncthreads();
  sm = red[0]+red[1]+red[2]+red[3];
  float inv = 1.0f / sm;
  #pragma unroll
  for(int u=0; u<16; u++) cT[j*Ci + tid + 256*u] = vals[u]*inv;
}

// ---- s-pass: per ki-chunk partial of s[b][jd]; 8 waves, wave = [32 b x 80 jd] of MFMA 16x16x32 ----
__global__ __launch_bounds__(512) void s_pass(const unsigned short* __restrict__ xb,
                                              const unsigned short* __restrict__ w2,
                                              const float* __restrict__ cT,
                                              float* __restrict__ spart){
  __shared__ unsigned short xs[128*64];    // [b][k] rows 128B, XOR-swizzled
  __shared__ unsigned short wsm[160*64];   // [jd][k] rows 128B, XOR-swizzled, pre-scaled by c
  const int tid = threadIdx.x, lane = tid & 63, wid = tid >> 6;
  const int wb = wid & 3, wj = wid >> 2;
  const int ki0 = blockIdx.x * CK;
  f32x4 acc[2][5];
  const f32x4 z = {0.f,0.f,0.f,0.f};
  #pragma unroll
  for(int m=0;m<2;m++){ acc[m][0]=z; acc[m][1]=z; acc[m][2]=z; acc[m][3]=z; acc[m][4]=z; }

  for(int step=0; step<CK/64; ++step){
    const int kb = ki0 + step*64;
    const int ib = kb & (Ci-1);       // chunk stays inside one k-slab, i base
    #pragma unroll
    for(int u=0; u<2; u++){           // stage x tile [128 b][64 ki]
      int e = tid + 512*u;
      int b = e >> 3, sg = e & 7;
      u16x8 v = *(const u16x8*)(xb + (size_t)b*KI + kb + sg*8);
      *(u16x8*)((char*)xs + b*128 + ((sg*16) ^ ((b&7)<<4))) = v;
    }
    #pragma unroll
    for(int u=0; u<3; u++){           // stage w tile [160 jd][64 ki] * c[i][j]
      int e = tid + 512*u;
      if(e < 1280){
        int jd = e >> 3, sg = e & 7;
        u16x8 v = *(const u16x8*)(w2 + (size_t)jd*KI + kb + sg*8);
        const float* cp = cT + (jd>>4)*Ci + ib + sg*8;
        float4 c0 = *(const float4*)cp;
        float4 c1 = *(const float4*)(cp+4);
        u16x8 o;
        o[0]=f2bf(bf2f(v[0])*c0.x); o[1]=f2bf(bf2f(v[1])*c0.y);
        o[2]=f2bf(bf2f(v[2])*c0.z); o[3]=f2bf(bf2f(v[3])*c0.w);
        o[4]=f2bf(bf2f(v[4])*c1.x); o[5]=f2bf(bf2f(v[5])*c1.y);
        o[6]=f2bf(bf2f(v[6])*c1.z); o[7]=f2bf(bf2f(v[7])*c1.w);
        *(u16x8*)((char*)wsm + jd*128 + ((sg*16) ^ ((jd&7)<<4))) = o;
      }
    }
    __syncthreads();
    #pragma unroll
    for(int ks=0; ks<2; ks++){
      const int kk2 = (ks*32 + ((lane>>4)<<3)) * 2;   // byte offset of 8-k group
      bf16x8 a[2];
      #pragma unroll
      for(int m=0;m<2;m++){
        int row = wb*32 + m*16 + (lane&15);
        a[m] = *(const bf16x8*)((const char*)xs + row*128 + (kk2 ^ ((row&7)<<4)));
      }
      #pragma unroll
      for(int n=0;n<5;n++){
        int row = wj*80 + n*16 + (lane&15);
        bf16x8 bb = *(const bf16x8*)((const char*)wsm + row*128 + (kk2 ^ ((row&7)<<4)));
        acc[0][n] = __builtin_amdgcn_mfma_f32_16x16x32_bf16(a[0], bb, acc[0][n], 0,0,0);
        acc[1][n] = __builtin_amdgcn_mfma_f32_16x16x32_bf16(a[1], bb, acc[1][n], 0,0,0);
      }
    }
    __syncthreads();
  }
  float* sp = spart + (size_t)blockIdx.x * (Bb*JDt);
  #pragma unroll
  for(int m=0;m<2;m++)
    #pragma unroll
    for(int n=0;n<5;n++)
      #pragma unroll
      for(int r=0;r<4;r++){
        int b  = wb*32 + m*16 + ((lane>>4)<<2) + r;     // D-frag: row=(lane>>4)*4+r
        int jd = wj*80 + n*16 + (lane&15);              //          col=lane&15
        sp[b*JDt + jd] = acc[m][n][r];
      }
}

// ---- reduce split-K partials + squash; writes v (f32, = d_out layout) and v_bfT ----
__global__ __launch_bounds__(256) void redsq(const float* __restrict__ spart,
                                             float* __restrict__ vout,
                                             unsigned short* __restrict__ vbT){
  const int b = blockIdx.x, tid = threadIdx.x;
  __shared__ float sq[JDt];
  __shared__ float scale[Dd];
  float s = 0.f;
  if(tid < JDt){
    const float* p = spart + b*JDt + tid;
    #pragma unroll 8
    for(int ch=0; ch<NCH; ch++) s += p[(size_t)ch*(Bb*JDt)];
    sq[tid] = s*s;
  }
  __syncthreads();
  if(tid < Dd){
    float m = 0.f;
    #pragma unroll
    for(int j=0;j<Jj;j++) m += sq[j*Dd + tid];
    scale[tid] = sqrtf(m) / (1.0f + m);    // v = s * sqrt(m)/(1+m)
  }
  __syncthreads();
  if(tid < JDt){
    float v = s * scale[tid & (Dd-1)];
    vout[b*JDt + tid] = v;
    vbT[tid*Bb + b] = f2bf(v);
  }
}

// ---- agree pass: Z_T[jd][ki] = sum_b v[jd][b]*x[b][ki], fused epilogue -> atomicAdd into bT ----
__global__ __launch_bounds__(256) void agree_pass(const unsigned short* __restrict__ xb,
                                                  const unsigned short* __restrict__ vbT,
                                                  const unsigned short* __restrict__ w2,
                                                  float* __restrict__ bT){
  __shared__ unsigned short xsT[64*128];   // [ki][b] rows 256B, swizzled (16 KB)
  __shared__ unsigned short vsm[160*128];  // [jd][b] rows 256B, swizzled (40 KB)
  const int tid = threadIdx.x, lane = tid & 63, wid = tid >> 6;
  const int wj = wid & 1, wk = wid >> 1;
  const int ki0 = blockIdx.x * 64;
  #pragma unroll
  for(int u=0; u<4; u++){                  // stage x transposed
    int e = tid + 256*u;
    int b = e >> 3, sg = e & 7;
    u16x8 v = *(const u16x8*)(xb + (size_t)b*KI + ki0 + sg*8);
    #pragma unroll
    for(int q=0; q<8; q++){
      int kil = sg*8 + q;
      *(unsigned short*)((char*)xsT + kil*256 + ((b*2) ^ ((kil&7)<<4))) = v[q];
    }
  }
  #pragma unroll
  for(int u=0; u<10; u++){                 // stage v
    int e = tid + 256*u;
    int jd = e >> 4, sg = e & 15;
    u16x8 v = *(const u16x8*)(vbT + jd*Bb + sg*8);
    *(u16x8*)((char*)vsm + jd*256 + ((sg*16) ^ ((jd&7)<<4))) = v;
  }
  __syncthreads();
  f32x4 acc[5][2];
  const f32x4 z = {0.f,0.f,0.f,0.f};
  #pragma unroll
  for(int m=0;m<5;m++){ acc[m][0]=z; acc[m][1]=z; }
  #pragma unroll
  for(int ks=0; ks<4; ks++){
    const int b2 = (ks*32 + ((lane>>4)<<3)) * 2;
    bf16x8 bfr[2];
    #pragma unroll
    for(int n=0;n<2;n++){
      int row = wk*32 + n*16 + (lane&15);
      bfr[n] = *(const bf16x8*)((const char*)xsT + row*256 + (b2 ^ ((row&7)<<4)));
    }
    #pragma unroll
    for(int m=0;m<5;m++){
      int row = wj*80 + m*16 + (lane&15);
      bf16x8 af = *(const bf16x8*)((const char*)vsm + row*256 + (b2 ^ ((row&7)<<4)));
      acc[m][0] = __builtin_amdgcn_mfma_f32_16x16x32_bf16(af, bfr[0], acc[m][0], 0,0,0);
      acc[m][1] = __builtin_amdgcn_mfma_f32_16x16x32_bf16(af, bfr[1], acc[m][1], 0,0,0);
    }
  }
  const int ibase = ki0 & (Ci-1);
  #pragma unroll
  for(int m=0;m<5;m++){
    int j = wj*5 + m;
    #pragma unroll
    for(int n=0;n<2;n++){
      int colg = ki0 + wk*32 + n*16 + (lane&15);
      float s = 0.f;
      #pragma unroll
      for(int r=0;r<4;r++){
        int jdrow = wj*80 + m*16 + ((lane>>4)<<2) + r;   // = j*16 + d
        s += acc[m][n][r] * bf2f(w2[(size_t)jdrow*KI + colg]);
      }
      s += __shfl_xor(s, 16);      // lanes l and l^16/l^32 share the same column (i)
      s += __shfl_xor(s, 32);
      if(lane < 16){
        int ig = ibase + wk*32 + n*16 + lane;
        atomicAdd(bT + j*Ci + ig, s * (1.0f/128.0f));
      }
    }
  }
}

extern "C" void kernel_launch(void* const* d_in, const int* in_sizes, int n_in,
                              void* d_out, int out_size, void* d_ws, size_t ws_size,
                              hipStream_t stream) {
  const float* x = (const float*)d_in[0];
  const float* W = (const float*)d_in[1];
  float* out = (float*)d_out;
  char* ws = (char*)d_ws;
  unsigned short* xbf = (unsigned short*)(ws + OFF_XB);
  unsigned short* w2  = (unsigned short*)(ws + OFF_W2);
  float* bT           = (float*)(ws + OFF_BT);
  float* cT           = (float*)(ws + OFF_CT);
  unsigned short* vbT = (unsigned short*)(ws + OFF_VBT);
  float* spart        = (float*)(ws + OFF_SP);

  hipMemsetAsync(bT, 0, SZ_BT, stream);          // routing logits start at 0 every call
  pack_x<<<8192, 256, 0, stream>>>(x, xbf);
  pack_w2<<<5120, 256, 0, stream>>>(W, w2);
  for(int t=0; t<3; t++){
    softmax_k<<<Jj, 256, 0, stream>>>(bT, cT);
    s_pass<<<NCH, 512, 0, stream>>>(xbf, w2, cT, spart);
    redsq<<<Bb, 256, 0, stream>>>(spart, out, vbT);
    if(t < 2) agree_pass<<<KI/64, 256, 0, stream>>>(xbf, vbT, w2, bT);
  }
}

// Round 2
// 228.444 us; speedup vs baseline: 1.0357x; 1.0357x over previous
//
#include <hip/hip_runtime.h>

// CapsNet dynamic routing, MI355X. Strategy: never materialize u_hat.
//  s-pass:    s[b][jd]  = sum_ki x_bf[b][ki] * (c[i][j] * W2[jd][ki])   (MFMA GEMM, split-K over 256 chunks)
//  agree:     Z_T[jd][ki] = sum_b v_bfT[jd][b] * x_bf[b][ki]; epilogue: b_ij[j][i] += (1/B) sum_{k,d} W2*Z_T
// R2: no hipMemsetAsync (50us rocclr fill!) — bT zeroed inside merged pack_all; t=0 softmax skipped (uniform c).

typedef __attribute__((ext_vector_type(8))) __bf16 bf16x8;
typedef __attribute__((ext_vector_type(4))) float  f32x4;
typedef __attribute__((ext_vector_type(8))) unsigned short u16x8;
typedef __attribute__((ext_vector_type(4))) unsigned short u16x4;

#define DI __device__ __forceinline__

DI float bf2f(unsigned short u){ unsigned int x = ((unsigned int)u) << 16; return __builtin_bit_cast(float, x); }
DI unsigned short f2bf(float f){
  unsigned int u = __builtin_bit_cast(unsigned int, f);
  u += 0x7fffu + ((u >> 16) & 1u);            // round-to-nearest-even
  return (unsigned short)(u >> 16);
}

constexpr int Ci = 4096, Kk = 32, Jj = 10, Dd = 16, Bb = 128;
constexpr int KI = Ci * Kk;    // 131072 flattened (k,i), ki = k*4096 + i
constexpr int JDt = Jj * Dd;   // 160, jd = j*16 + d
constexpr int NCH = 256, CK = 512;  // s-pass split-K chunks

// workspace layout (bytes)
constexpr size_t OFF_XB = 0;
constexpr size_t SZ_XB  = (size_t)Bb * KI * 2;        // 33,554,432
constexpr size_t OFF_W2 = OFF_XB + SZ_XB;
constexpr size_t SZ_W2  = (size_t)JDt * KI * 2;       // 41,943,040
constexpr size_t OFF_BT = OFF_W2 + SZ_W2;
constexpr size_t SZ_BT  = (size_t)Jj * Ci * 4;        // 163,840  (b_ij transposed [j][i])
constexpr size_t OFF_CT = OFF_BT + SZ_BT;             // c transposed [j][i]
constexpr size_t OFF_VBT = OFF_CT + SZ_BT;
constexpr size_t SZ_VBT = (size_t)JDt * Bb * 2;       // 40,960   (v bf16, [jd][b])
constexpr size_t OFF_SP = OFF_VBT + SZ_VBT;
constexpr size_t SZ_SP  = (size_t)NCH * Bb * JDt * 4; // 20,971,520
// total ~96.8 MB

// ---- merged pack: blocks [0,5120) transpose W -> w2; [5120,13312) cast x; [13312,13352) zero bT ----
__global__ __launch_bounds__(256) void pack_all(const float* __restrict__ x, const float* __restrict__ W,
                                                unsigned short* __restrict__ xbf, unsigned short* __restrict__ w2,
                                                float* __restrict__ bT){
  __shared__ float tile[64][65];
  const int bid = blockIdx.x;
  if(bid < 5120){
    // pack W: f32 W[i][m] (m = jd*32+k, row len 5120) -> bf16 W2[m][i] (64x64 tiled transpose)
    const int mt = bid % 80, it = bid / 80;
    const int m0 = mt * 64, i0 = it * 64;
    #pragma unroll
    for(int u=0; u<4; u++){
      int e = threadIdx.x + 256*u;
      int il = e >> 4, q = e & 15;
      float4 v = *(const float4*)(W + (size_t)(i0+il)*5120 + m0 + q*4);
      tile[il][q*4+0]=v.x; tile[il][q*4+1]=v.y; tile[il][q*4+2]=v.z; tile[il][q*4+3]=v.w;
    }
    __syncthreads();
    #pragma unroll
    for(int u=0; u<4; u++){
      int e = threadIdx.x + 256*u;
      int ml = e >> 4, q = e & 15;
      u16x4 o;
      o[0]=f2bf(tile[q*4+0][ml]); o[1]=f2bf(tile[q*4+1][ml]);
      o[2]=f2bf(tile[q*4+2][ml]); o[3]=f2bf(tile[q*4+3][ml]);
      *(u16x4*)(w2 + (size_t)(m0+ml)*Ci + i0 + q*4) = o;
    }
  } else if(bid < 13312){
    // pack x: f32 [B][K][C] -> bf16 [B][KI] (same flat order), 8 elems/thread
    const size_t e = (size_t)(bid - 5120) * 256 + threadIdx.x;
    const float4* xv = (const float4*)x;
    float4 a = xv[e*2], b = xv[e*2+1];
    u16x8 o;
    o[0]=f2bf(a.x); o[1]=f2bf(a.y); o[2]=f2bf(a.z); o[3]=f2bf(a.w);
    o[4]=f2bf(b.x); o[5]=f2bf(b.y); o[6]=f2bf(b.z); o[7]=f2bf(b.w);
    *(u16x8*)(xbf + e*8) = o;
  } else {
    // zero bT: 40 blocks x 256 threads x 16B = 163840 B
    const int zb = bid - 13312;
    ((float4*)bT)[zb*256 + threadIdx.x] = float4{0.f,0.f,0.f,0.f};
  }
}

// ---- softmax over i per class j: cT[j][i] = softmax_i(bT[j][i]) ----
__global__ __launch_bounds__(256) void softmax_k(const float* __restrict__ bT, float* __restrict__ cT){
  const int j = blockIdx.x, tid = threadIdx.x, lane = tid & 63, wid = tid >> 6;
  __shared__ float red[4];
  float vals[16];
  float mx = -3.4e38f;
  #pragma unroll
  for(int u=0; u<16; u++){ vals[u] = bT[j*Ci + tid + 256*u]; mx = fmaxf(mx, vals[u]); }
  #pragma unroll
  for(int o=32; o>0; o>>=1) mx = fmaxf(mx, __shfl_xor(mx, o));
  if(lane == 0) red[wid] = mx;
  __syncthreads();
  mx = fmaxf(fmaxf(red[0],red[1]), fmaxf(red[2],red[3]));
  float sm = 0.f;
  #pragma unroll
  for(int u=0; u<16; u++){ vals[u] = expf(vals[u]-mx); sm += vals[u]; }
  #pragma unroll
  for(int o=32; o>0; o>>=1) sm += __shfl_xor(sm, o);
  __syncthreads();
  if(lane == 0) red[wid] = sm;
  __syncthreads();
  sm = red[0]+red[1]+red[2]+red[3];
  float inv = 1.0f / sm;
  #pragma unroll
  for(int u=0; u<16; u++) cT[j*Ci + tid + 256*u] = vals[u]*inv;
}

// ---- s-pass: per ki-chunk partial of s[b][jd]; 8 waves, wave = [32 b x 80 jd] of MFMA 16x16x32 ----
// cT==nullptr -> uniform c = 1/4096 (iteration 0: softmax of zeros)
__global__ __launch_bounds__(512) void s_pass(const unsigned short* __restrict__ xb,
                                              const unsigned short* __restrict__ w2,
                                              const float* __restrict__ cT,
                                              float* __restrict__ spart){
  __shared__ unsigned short xs[128*64];    // [b][k] rows 128B, XOR-swizzled
  __shared__ unsigned short wsm[160*64];   // [jd][k] rows 128B, XOR-swizzled, pre-scaled by c
  const int tid = threadIdx.x, lane = tid & 63, wid = tid >> 6;
  const int wb = wid & 3, wj = wid >> 2;
  const int ki0 = blockIdx.x * CK;
  f32x4 acc[2][5];
  const f32x4 z = {0.f,0.f,0.f,0.f};
  #pragma unroll
  for(int m=0;m<2;m++){ acc[m][0]=z; acc[m][1]=z; acc[m][2]=z; acc[m][3]=z; acc[m][4]=z; }

  for(int step=0; step<CK/64; ++step){
    const int kb = ki0 + step*64;
    const int ib = kb & (Ci-1);       // chunk stays inside one k-slab, i base
    #pragma unroll
    for(int u=0; u<2; u++){           // stage x tile [128 b][64 ki]
      int e = tid + 512*u;
      int b = e >> 3, sg = e & 7;
      u16x8 v = *(const u16x8*)(xb + (size_t)b*KI + kb + sg*8);
      *(u16x8*)((char*)xs + b*128 + ((sg*16) ^ ((b&7)<<4))) = v;
    }
    #pragma unroll
    for(int u=0; u<3; u++){           // stage w tile [160 jd][64 ki] * c[i][j]
      int e = tid + 512*u;
      if(e < 1280){
        int jd = e >> 3, sg = e & 7;
        u16x8 v = *(const u16x8*)(w2 + (size_t)jd*KI + kb + sg*8);
        float cc[8];
        if(cT){
          const float* cp = cT + (jd>>4)*Ci + ib + sg*8;
          float4 c0 = *(const float4*)cp;
          float4 c1 = *(const float4*)(cp+4);
          cc[0]=c0.x; cc[1]=c0.y; cc[2]=c0.z; cc[3]=c0.w;
          cc[4]=c1.x; cc[5]=c1.y; cc[6]=c1.z; cc[7]=c1.w;
        } else {
          #pragma unroll
          for(int q=0;q<8;q++) cc[q] = (1.0f/4096.0f);
        }
        u16x8 o;
        #pragma unroll
        for(int q=0;q<8;q++) o[q] = f2bf(bf2f(v[q])*cc[q]);
        *(u16x8*)((char*)wsm + jd*128 + ((sg*16) ^ ((jd&7)<<4))) = o;
      }
    }
    __syncthreads();
    #pragma unroll
    for(int ks=0; ks<2; ks++){
      const int kk2 = (ks*32 + ((lane>>4)<<3)) * 2;   // byte offset of 8-k group
      bf16x8 a[2];
      #pragma unroll
      for(int m=0;m<2;m++){
        int row = wb*32 + m*16 + (lane&15);
        a[m] = *(const bf16x8*)((const char*)xs + row*128 + (kk2 ^ ((row&7)<<4)));
      }
      #pragma unroll
      for(int n=0;n<5;n++){
        int row = wj*80 + n*16 + (lane&15);
        bf16x8 bb = *(const bf16x8*)((const char*)wsm + row*128 + (kk2 ^ ((row&7)<<4)));
        acc[0][n] = __builtin_amdgcn_mfma_f32_16x16x32_bf16(a[0], bb, acc[0][n], 0,0,0);
        acc[1][n] = __builtin_amdgcn_mfma_f32_16x16x32_bf16(a[1], bb, acc[1][n], 0,0,0);
      }
    }
    __syncthreads();
  }
  float* sp = spart + (size_t)blockIdx.x * (Bb*JDt);
  #pragma unroll
  for(int m=0;m<2;m++)
    #pragma unroll
    for(int n=0;n<5;n++)
      #pragma unroll
      for(int r=0;r<4;r++){
        int b  = wb*32 + m*16 + ((lane>>4)<<2) + r;     // D-frag: row=(lane>>4)*4+r
        int jd = wj*80 + n*16 + (lane&15);              //          col=lane&15
        sp[b*JDt + jd] = acc[m][n][r];
      }
}

// ---- reduce split-K partials + squash; writes v (f32, = d_out layout) and v_bfT ----
__global__ __launch_bounds__(256) void redsq(const float* __restrict__ spart,
                                             float* __restrict__ vout,
                                             unsigned short* __restrict__ vbT){
  const int b = blockIdx.x, tid = threadIdx.x;
  __shared__ float sq[JDt];
  __shared__ float scale[Dd];
  float s = 0.f;
  if(tid < JDt){
    const float* p = spart + b*JDt + tid;
    #pragma unroll 8
    for(int ch=0; ch<NCH; ch++) s += p[(size_t)ch*(Bb*JDt)];
    sq[tid] = s*s;
  }
  __syncthreads();
  if(tid < Dd){
    float m = 0.f;
    #pragma unroll
    for(int j=0;j<Jj;j++) m += sq[j*Dd + tid];
    scale[tid] = sqrtf(m) / (1.0f + m);    // v = s * sqrt(m)/(1+m)
  }
  __syncthreads();
  if(tid < JDt){
    float v = s * scale[tid & (Dd-1)];
    vout[b*JDt + tid] = v;
    vbT[tid*Bb + b] = f2bf(v);
  }
}

// ---- agree pass: Z_T[jd][ki] = sum_b v[jd][b]*x[b][ki], fused epilogue -> atomicAdd into bT ----
__global__ __launch_bounds__(256) void agree_pass(const unsigned short* __restrict__ xb,
                                                  const unsigned short* __restrict__ vbT,
                                                  const unsigned short* __restrict__ w2,
                                                  float* __restrict__ bT){
  __shared__ unsigned short xsT[64*128];   // [ki][b] rows 256B, swizzled (16 KB)
  __shared__ unsigned short vsm[160*128];  // [jd][b] rows 256B, swizzled (40 KB)
  const int tid = threadIdx.x, lane = tid & 63, wid = tid >> 6;
  const int wj = wid & 1, wk = wid >> 1;
  const int ki0 = blockIdx.x * 64;
  #pragma unroll
  for(int u=0; u<4; u++){                  // stage x transposed
    int e = tid + 256*u;
    int b = e >> 3, sg = e & 7;
    u16x8 v = *(const u16x8*)(xb + (size_t)b*KI + ki0 + sg*8);
    #pragma unroll
    for(int q=0; q<8; q++){
      int kil = sg*8 + q;
      *(unsigned short*)((char*)xsT + kil*256 + ((b*2) ^ ((kil&7)<<4))) = v[q];
    }
  }
  #pragma unroll
  for(int u=0; u<10; u++){                 // stage v
    int e = tid + 256*u;
    int jd = e >> 4, sg = e & 15;
    u16x8 v = *(const u16x8*)(vbT + jd*Bb + sg*8);
    *(u16x8*)((char*)vsm + jd*256 + ((sg*16) ^ ((jd&7)<<4))) = v;
  }
  __syncthreads();
  f32x4 acc[5][2];
  const f32x4 z = {0.f,0.f,0.f,0.f};
  #pragma unroll
  for(int m=0;m<5;m++){ acc[m][0]=z; acc[m][1]=z; }
  #pragma unroll
  for(int ks=0; ks<4; ks++){
    const int b2 = (ks*32 + ((lane>>4)<<3)) * 2;
    bf16x8 bfr[2];
    #pragma unroll
    for(int n=0;n<2;n++){
      int row = wk*32 + n*16 + (lane&15);
      bfr[n] = *(const bf16x8*)((const char*)xsT + row*256 + (b2 ^ ((row&7)<<4)));
    }
    #pragma unroll
    for(int m=0;m<5;m++){
      int row = wj*80 + m*16 + (lane&15);
      bf16x8 af = *(const bf16x8*)((const char*)vsm + row*256 + (b2 ^ ((row&7)<<4)));
      acc[m][0] = __builtin_amdgcn_mfma_f32_16x16x32_bf16(af, bfr[0], acc[m][0], 0,0,0);
      acc[m][1] = __builtin_amdgcn_mfma_f32_16x16x32_bf16(af, bfr[1], acc[m][1], 0,0,0);
    }
  }
  const int ibase = ki0 & (Ci-1);
  #pragma unroll
  for(int m=0;m<5;m++){
    int j = wj*5 + m;
    #pragma unroll
    for(int n=0;n<2;n++){
      int colg = ki0 + wk*32 + n*16 + (lane&15);
      float s = 0.f;
      #pragma unroll
      for(int r=0;r<4;r++){
        int jdrow = wj*80 + m*16 + ((lane>>4)<<2) + r;   // = j*16 + d
        s += acc[m][n][r] * bf2f(w2[(size_t)jdrow*KI + colg]);
      }
      s += __shfl_xor(s, 16);      // lanes l and l^16/l^32 share the same column (i)
      s += __shfl_xor(s, 32);
      if(lane < 16){
        int ig = ibase + wk*32 + n*16 + lane;
        atomicAdd(bT + j*Ci + ig, s * (1.0f/128.0f));
      }
    }
  }
}

extern "C" void kernel_launch(void* const* d_in, const int* in_sizes, int n_in,
                              void* d_out, int out_size, void* d_ws, size_t ws_size,
                              hipStream_t stream) {
  const float* x = (const float*)d_in[0];
  const float* W = (const float*)d_in[1];
  float* out = (float*)d_out;
  char* ws = (char*)d_ws;
  unsigned short* xbf = (unsigned short*)(ws + OFF_XB);
  unsigned short* w2  = (unsigned short*)(ws + OFF_W2);
  float* bT           = (float*)(ws + OFF_BT);
  float* cT           = (float*)(ws + OFF_CT);
  unsigned short* vbT = (unsigned short*)(ws + OFF_VBT);
  float* spart        = (float*)(ws + OFF_SP);

  pack_all<<<13352, 256, 0, stream>>>(x, W, xbf, w2, bT);   // also zeroes bT
  for(int t=0; t<3; t++){
    if(t > 0) softmax_k<<<Jj, 256, 0, stream>>>(bT, cT);
    s_pass<<<NCH, 512, 0, stream>>>(xbf, w2, (t==0)? nullptr : cT, spart);
    redsq<<<Bb, 256, 0, stream>>>(spart, out, vbT);
    if(t < 2) agree_pass<<<KI/64, 256, 0, stream>>>(xbf, vbT, w2, bT);
  }
}